// Round 1
// baseline (288.943 us; speedup 1.0000x reference)
//
#include <hip/hip_runtime.h>
#include <cstdint>
#include <cstddef>

#define N_INST 100
#define HW (640 * 960)          /* 614400 */
#define PIX_THR 0.4f
#define FRAC_THR 0.03f

// d_out layout (float32):
//   [0 .. 100)                      cls_prob_s
//   [100 .. 100+N*HW)               keep_masks
//   [100+N*HW .. 100+N*HW+100)      cls_idx_s (as float)
//   [100+N*HW+100 .. +100)          keep_flags (0/1 float)
#define OUT_MASKS_OFF 100
#define OUT_CLSIDX_OFF (100 + (size_t)N_INST * HW)
#define OUT_FLAGS_OFF (100 + (size_t)N_INST * HW + N_INST)

// ws layout:
//   [0]      int    ord[100]
//   [512]    int    keep[100]
//   [1024]   uint   mask_sum[100]
//   [2048]   uint   pair_cnt[100*100]   (40000 B)
//   [65536]  uint   code[HW]            (2457600 B)

__global__ void k0_sort(const float* __restrict__ cls_prob,
                        const int* __restrict__ cls_idx,
                        int* __restrict__ ord,
                        float* __restrict__ out) {
    int i = threadIdx.x;
    if (i >= N_INST) return;
    float pi = cls_prob[i];
    int rank = 0;
    for (int j = 0; j < N_INST; ++j) {
        float pj = cls_prob[j];
        // argsort(-cls_prob) stable ascending == descending by value, ties by index
        rank += (pj > pi) || (pj == pi && j < i);
    }
    ord[rank] = i;
    out[rank] = pi;                              // cls_prob_s
    out[OUT_CLSIDX_OFF + rank] = (float)cls_idx[i]; // cls_idx_s
}

__global__ __launch_bounds__(256) void k1_softmax(
    const float* __restrict__ mask,
    const int* __restrict__ ord,
    unsigned* __restrict__ mask_sum,
    unsigned* __restrict__ pair_cnt,
    unsigned* __restrict__ code) {
    __shared__ int sord[N_INST];
    __shared__ unsigned ssum[N_INST];
    int t = threadIdx.x;
    if (t < N_INST) {
        sord[t] = ord[t];
        ssum[t] = 0u;
    }
    __syncthreads();

    int p = blockIdx.x * 256 + t;   // grid sized exactly HW/256

    float v[N_INST];
#pragma unroll
    for (int i = 0; i < N_INST; ++i)
        v[i] = mask[(size_t)sord[i] * HW + p];

    // exact max + top-2 (positions in sorted order)
    float m = v[0];
    int p1 = 0;
    float m2 = -3.4e38f;
    int p2 = 0;
#pragma unroll
    for (int i = 1; i < N_INST; ++i) {
        if (v[i] > m) { m2 = m; p2 = p1; m = v[i]; p1 = i; }
        else if (v[i] > m2) { m2 = v[i]; p2 = i; }
    }

    // reference-style softmax denominator: sum exp(v - m) in instance order
    float d = 0.0f;
#pragma unroll
    for (int i = 0; i < N_INST; ++i)
        d += expf(v[i] - m);

    float sm1 = 1.0f / d;            // exp(0) == 1 exactly
    float sm2 = expf(m2 - m) / d;
    bool q1 = (sm1 >= PIX_THR);
    bool q2 = (sm2 >= PIX_THR);

    unsigned c = 0u;
    if (q1) {
        atomicAdd(&ssum[p1], 1u);
        if (q2) {
            atomicAdd(&ssum[p2], 1u);
            int a = min(p1, p2);
            int b = max(p1, p2);
            atomicAdd(&pair_cnt[a * N_INST + b], 1u);
            c = (unsigned)(a + 1) | ((unsigned)(b + 1) << 8);
        } else {
            c = (unsigned)(p1 + 1);
        }
    }
    code[p] = c;

    __syncthreads();
    if (t < N_INST && ssum[t] != 0u)
        atomicAdd(&mask_sum[t], ssum[t]);
}

__global__ void k2_scan(const unsigned* __restrict__ mask_sum,
                        const unsigned* __restrict__ pair_cnt,
                        const int* __restrict__ ord,
                        const int* __restrict__ cls_idx,
                        int* __restrict__ keep,
                        float* __restrict__ out) {
    __shared__ unsigned spair[N_INST * N_INST];   // 40 KB
    __shared__ int scls[N_INST];
    __shared__ unsigned sms[N_INST];
    __shared__ int skeep[N_INST];
    int t = threadIdx.x;  // 256 threads
    for (int i = t; i < N_INST * N_INST; i += 256)
        spair[i] = pair_cnt[i];
    if (t < N_INST) {
        scls[t] = cls_idx[ord[t]];
        sms[t] = mask_sum[t];
    }
    __syncthreads();

    for (int b = 0; b < N_INST; ++b) {
        if (t < 64) {
            unsigned cnt = 0u;
            for (int a = t; a < b; a += 64)
                if (skeep[a] && scls[a] == scls[b])
                    cnt += spair[a * N_INST + b];
#pragma unroll
            for (int off = 32; off; off >>= 1)
                cnt += __shfl_down((int)cnt, off);
            if (t == 0) {
                unsigned ms = sms[b];
                float overlap = (float)cnt / fmaxf((float)ms, 1.0f);
                bool degen = (ms == 0u) || (ms == (unsigned)HW);
                bool skip = degen || (overlap > FRAC_THR);
                skeep[b] = skip ? 0 : 1;
            }
        }
        __syncthreads();
    }

    if (t < N_INST) {
        keep[t] = skeep[t];
        out[OUT_FLAGS_OFF + t] = (float)skeep[t];
    }
}

__global__ __launch_bounds__(256) void k3_write(
    const float* __restrict__ mask,
    const int* __restrict__ ord,
    const int* __restrict__ keep,
    const unsigned* __restrict__ code,
    float* __restrict__ out) {
    __shared__ int skeep[N_INST];
    __shared__ int sord[N_INST];
    if (threadIdx.x < N_INST) {
        skeep[threadIdx.x] = keep[threadIdx.x];
        sord[threadIdx.x] = ord[threadIdx.x];
    }
    __syncthreads();

    int i = blockIdx.y;
    int p = blockIdx.x * 256 + threadIdx.x;

    unsigned c = code[p];
    int a = (int)(c & 0xFFu) - 1;
    int b = (int)(c >> 8) - 1;

    bool assigned;
    if (a == i)      assigned = (skeep[i] != 0);                       // earliest candidate
    else if (b == i) assigned = (skeep[i] != 0) && (skeep[a] == 0);    // second candidate
    else             assigned = false;

    float val = 0.0f;
    if (assigned)
        val = mask[(size_t)sord[i] * HW + p];
    out[OUT_MASKS_OFF + (size_t)i * HW + p] = val;
}

extern "C" void kernel_launch(void* const* d_in, const int* in_sizes, int n_in,
                              void* d_out, int out_size, void* d_ws, size_t ws_size,
                              hipStream_t stream) {
    const float* cls_prob = (const float*)d_in[0];
    const float* mask = (const float*)d_in[1];
    const int* cls_idx = (const int*)d_in[2];
    float* out = (float*)d_out;

    char* ws = (char*)d_ws;
    int* ord = (int*)(ws + 0);
    int* keep = (int*)(ws + 512);
    unsigned* mask_sum = (unsigned*)(ws + 1024);
    unsigned* pair_cnt = (unsigned*)(ws + 2048);
    unsigned* code = (unsigned*)(ws + 65536);

    // zero counters (mask_sum + pair_cnt)
    hipMemsetAsync(ws + 1024, 0, 1024 + 40000, stream);

    k0_sort<<<1, 128, 0, stream>>>(cls_prob, cls_idx, ord, out);
    k1_softmax<<<HW / 256, 256, 0, stream>>>(mask, ord, mask_sum, pair_cnt, code);
    k2_scan<<<1, 256, 0, stream>>>(mask_sum, pair_cnt, ord, cls_idx, keep, out);
    k3_write<<<dim3(HW / 256, N_INST), 256, 0, stream>>>(mask, ord, keep, code, out);
}